// Round 16
// baseline (391.305 us; speedup 1.0000x reference)
//
#include <hip/hip_runtime.h>
#include <math.h>

// ---------------------------------------------------------------------------
// JointsGait fused v15 = R15 head/prep (best: 344.3us) + gcn re-blocked as
// 128-thread / 1-graph / 2-wave blocks.
// layer = ReLU(((A_hat @ H) @ W + b) * att) == ReLU((A_hat @ (H @ W) + b) * att)
//
// R16: gcn sits 2.4x above its issue floor - pure uncovered latency at
// 8 waves/CU. Untested axis: same occupancy, but 4 independent 2-wave
// convoys per CU instead of 2x 4-wave convoys (more independent dependency
// streams; barriers sync only 2 waves). R10's full independence spilled
// (acc[2][16]); this is the spill-safe point: 1 graph/block, 2 waves
// splitting DOUT -> acc[2][8]=64 VGPR at bounds(128,2) (256-reg cap).
//  * 32-row slabs (2 mtiles), A-table 32x32 -> stage2 = 1 MFMA (K=32).
//  * Zt strips read only rows 0-31 (all freshly written): no zero-init.
//  * LDS = 2x16KB dbuf + 2x4KB strips = 40960B -> exactly 4 blocks/CU.
//  * head: fcW B-fragment pack (R15, -31us). prep grid 2048.
// ---------------------------------------------------------------------------

typedef _Float16 f16;
typedef _Float16 v2h __attribute__((ext_vector_type(2)));
typedef _Float16 v4h __attribute__((ext_vector_type(4)));
typedef _Float16 v8h __attribute__((ext_vector_type(8)));
typedef float    v4f __attribute__((ext_vector_type(4)));

namespace {

constexpr int BA[19] = {15,13,16,14,11, 5, 6, 5, 5, 6, 7, 8, 1, 0, 0, 1, 2, 3, 4};
constexpr int BB[19] = {13,11,14,12,12,11,12, 6, 7, 8, 9,10, 2, 1, 2, 3, 4, 5, 6};
constexpr float DINV[17] = {
  0.57735026919f, 0.5f, 0.5f, 0.57735026919f, 0.57735026919f,
  0.44721359550f, 0.44721359550f, 0.57735026919f, 0.57735026919f,
  0.70710678119f, 0.70710678119f, 0.5f, 0.5f,
  0.57735026919f, 0.57735026919f, 0.70710678119f, 0.70710678119f};

// H element index with XOR-chunk swizzle (row stride 256 f16 = 512B).
__device__ __forceinline__ int hswz(int row, int k){
  return row*256 + (k & ~63) + (((((k>>3)&7) ^ (row&7)))<<3) + (k&7);
}
// Zt strip: [32 cols][64 j] f16; f(c) = ((c&7)<<3) ^ ((c&8)<<2).
__device__ __forceinline__ int zswz(int c, int r){
  return c*64 + (r ^ ((c&7)<<3) ^ ((c&8)<<2));
}

__device__ __forceinline__ void ldh2(const f16* p, float* d){
  const v2h v = *(const v2h*)p; d[0]=v[0]; d[1]=v[1];
}

// ---- layer: stage1 Z=H@W (MFMA) -> wave-private Zt -> stage2 A-mix (MFMA) --
// 1 graph (32-row slab, rows 17-31 pad), 2 waves splitting DOUT.
// D-frag convention (16x16x32): lane (q,m): A[row=m][k=q*8+jj],
// B[k=q*8+jj][n=m], D[row=q*4+ii][col=m].
// stage2: A_op = Z^T (strip v8h, K=32), B = A_blk 32x32 const regs ->
//   lane holds H'[mt*16+m][cb+q*4+ii] -> relu((.+b)*att) -> v4h hswz write.
template<int KP, int DOUT>
__device__ __forceinline__ void layer_phase(const f16* __restrict__ src,
    f16* __restrict__ dst, f16* ztw,
    const f16* __restrict__ wp, const float* __restrict__ bias,
    const float (&av)[2], const v8h (&Bfrag)[2],
    int w, int m, int q)
{
  constexpr int NKS = KP/32;
  constexpr int NTW = DOUT/32;            // per-wave 16-col tiles (2,4,8)
  constexpr int NPASS = NTW/2;            // 32-col strip passes

  v4f acc[2][NTW];
  #pragma unroll
  for (int a=0;a<2;++a)
    #pragma unroll
    for (int b=0;b<NTW;++b) acc[a][b] = v4f{0.f,0.f,0.f,0.f};

  #pragma unroll
  for (int ks=0; ks<NKS; ++ks){
    v8h af[2];
    #pragma unroll
    for (int mt=0;mt<2;++mt)
      af[mt] = *(const v8h*)(src + hswz(mt*16+m, ks*32 + q*8));
    #pragma unroll
    for (int nt=0;nt<NTW;++nt){
      const v8h bf = *(const v8h*)(wp + ((((w*NTW+nt)*NKS + ks)*64 + q*16 + m)<<3));
      #pragma unroll
      for (int mt=0;mt<2;++mt)
        acc[mt][nt] = __builtin_amdgcn_mfma_f32_16x16x32_f16(af[mt], bf, acc[mt][nt], 0,0,0);
    }
  }

  #pragma unroll
  for (int p=0;p<NPASS;++p){
    // Zt write: this pass's 32 cols (wave-private strip)
    #pragma unroll
    for (int ct2=0;ct2<2;++ct2){
      #pragma unroll
      for (int mt=0;mt<2;++mt){
        const v4f a4 = acc[mt][p*2+ct2];
        v4h z;
        #pragma unroll
        for (int ii=0;ii<4;++ii) z[ii] = (f16)a4[ii];
        *(v4h*)(ztw + zswz(ct2*16+m, mt*16+q*4)) = z;
      }
    }
    // stage2 (K=32 single MFMA per (mt,ct2); same-wave LDS ordering)
    #pragma unroll
    for (int ct2=0;ct2<2;++ct2){
      const v8h za = *(const v8h*)(ztw + zswz(ct2*16+m, q*8));
      const v4f z4 = v4f{0.f,0.f,0.f,0.f};
      v4f a2[2];
      #pragma unroll
      for (int mt=0;mt<2;++mt)
        a2[mt] = __builtin_amdgcn_mfma_f32_16x16x32_f16(za, Bfrag[mt], z4, 0,0,0);
      const int cb = w*(DOUT/2) + p*32 + ct2*16 + q*4;
      const v4f b4 = *(const v4f*)(bias + cb);
      #pragma unroll
      for (int mt=0;mt<2;++mt){
        v4h o;
        #pragma unroll
        for (int ii=0;ii<4;++ii)
          o[ii] = (f16)fmaxf((a2[mt][ii] + b4[ii])*av[mt], 0.f);
        *(v4h*)(dst + hswz(mt*16+m, cb)) = o;
      }
    }
  }
}

} // namespace

// ---------------- prep: Wpack + fcW B-frag pack + 32x32 A-table + BN --------
__global__ void prep_kernel(
    const float* __restrict__ W1, const float* __restrict__ W2,
    const float* __restrict__ W3, const float* __restrict__ W4,
    const float* __restrict__ W5, const float* __restrict__ W6,
    const float* __restrict__ W7, const float* __restrict__ W8,
    const float* __restrict__ W9,
    const float* __restrict__ B1, const float* __restrict__ B2,
    const float* __restrict__ B3, const float* __restrict__ B4,
    const float* __restrict__ B5, const float* __restrict__ B6,
    const float* __restrict__ B7, const float* __restrict__ B8,
    const float* __restrict__ B9,
    const float* __restrict__ fcW, const float* __restrict__ bng,
    const float* __restrict__ bnb, const float* __restrict__ bnrm,
    const float* __restrict__ bnrv, const float* __restrict__ att,
    f16* __restrict__ wt, f16* __restrict__ At32, f16* __restrict__ fcWh,
    float* __restrict__ bnsc, float* __restrict__ bnsh,
    float* __restrict__ bcat, float* __restrict__ attp, int G)
{
  const int idx = blockIdx.x*blockDim.x + threadIdx.x;
  const int stride = gridDim.x*blockDim.x;
  const float* Ws[9] = {W1,W2,W3,W4,W5,W6,W7,W8,W9};
  const float* Bs[9] = {B1,B2,B3,B4,B5,B6,B7,B8,B9};
  const int DINs[9]  = {2,64,64,64,128,128,128,256,256};
  const int DOUTs[9] = {64,64,64,128,128,128,256,256,256};
  const int KPs[9]   = {32,64,64,64,128,128,128,256,256};
  const int OFFs[9]  = {0,2048,6144,10240,18432,34816,51200,83968,149504};
  const int BOFFs[9] = {0,64,128,192,320,448,576,832,1088};
  for (int l=0;l<9;++l){
    const float* W = Ws[l];
    const int DIN=DINs[l], DOUT=DOUTs[l], KP=KPs[l], NKS=KP>>5;
    f16* dst = wt + OFFs[l];
    const int n = DOUT*KP;
    for (int i=idx;i<n;i+=stride){
      // Wpack[(((ct*NKS+ks)*4+q)*16+m)*8+jj] = W[ks*32+q*8+jj][ct*16+m]
      const int jj = i&7, mm = (i>>3)&15, qq = (i>>7)&3, r2 = i>>9;
      const int ks = r2 & (NKS-1), ct = r2 / NKS;
      const int k = ks*32 + qq*8 + jj, c = ct*16 + mm;
      dst[i] = (k<DIN) ? (f16)W[k*DOUT+c] : (f16)0.f;
    }
    for (int i=idx;i<DOUT;i+=stride) bcat[BOFFs[l]+i] = Bs[l][i];
  }
  // 32x32 A-table: rows/cols 17-31 zero, symmetric.
  for (int i=idx;i<32*32;i+=stride){
    const int r = i>>5, j = i&31;
    float v = 0.f;
    if (r<17 && j<17){
      bool adj = (r==j);
      #pragma unroll
      for (int e=0;e<19;++e)
        adj = adj || (BA[e]==r && BB[e]==j) || (BA[e]==j && BB[e]==r);
      if (adj) v = DINV[r]*DINV[j];
    }
    At32[i] = (f16)v;
  }
  // fcW B-fragment pack, per scale s (256x256, NKS=8):
  // fcWh[s*65536 + ((ct*8+ks)*64 + q*16+m)*8+jj] = fcW[s][ct*16+m][ks*32+q*8+jj]
  for (int i=idx;i<6*65536;i+=stride){
    const int s = i>>16, j = i&65535;
    const int jj = j&7, mm = (j>>3)&15, qq = (j>>7)&3, r2 = j>>9;
    const int ks = r2&7, ct = r2>>3;
    const int k = ks*32 + qq*8 + jj, c = ct*16 + mm;
    fcWh[i] = (f16)fcW[(size_t)s*65536 + c*256 + k];
  }
  for (int i=idx;i<1536;i+=stride){
    const float sc = bng[i] * rsqrtf(bnrv[i] + 1e-5f);
    bnsc[i] = sc; bnsh[i] = bnb[i] - bnrm[i]*sc;
  }
  for (int i=idx;i<G*32;i+=stride){
    const int g = i>>5, j = i&31;
    attp[i] = (j<17) ? att[(size_t)g*17 + j] : 0.f;
  }
}

// ---------------- fused GCN: 1 graph/block, 2 waves, 1 barrier/layer --------
__global__ __launch_bounds__(128, 2)
void gcn_kernel(const float* __restrict__ x, const f16* __restrict__ wt,
                const f16* __restrict__ At32, const float* __restrict__ attp,
                const float* __restrict__ bcat,
                f16* __restrict__ pooled, int G)
{
  __shared__ __align__(16) f16 Hb[2][32*256];   // 2 x 16384 B
  __shared__ __align__(16) f16 Zt[2][2048];     // 2 waves x 4KB strips
  const int t = threadIdx.x, w = t>>6, lane = t&63;
  const int m = lane&15, q = lane>>4;
  const int gg = blockIdx.x;                    // grid == G
  f16* ztw = Zt[w];

  // persistent 32x32 A-table B-fragments (K=32) + att rows
  v8h Bfrag[2];
  #pragma unroll
  for (int mt=0;mt<2;++mt)
    Bfrag[mt] = *(const v8h*)(At32 + (mt*16+m)*32 + q*8);
  float av[2];
  #pragma unroll
  for (int mt=0;mt<2;++mt) av[mt] = attp[(size_t)gg*32 + mt*16 + m];

  // init H: rows 0..31 x cols 0..31 (layer-1 KP=32); x in rows<17, cols<2
  {
    const int kk = t&31, rg = t>>5;             // 4 row-groups x 8 rows
    #pragma unroll
    for (int r8=0;r8<8;++r8){
      const int rr = rg*8 + r8;
      float v = 0.f;
      if (kk < 2 && rr < 17) v = x[(size_t)gg*34 + rr*2 + kk];
      Hb[0][hswz(rr, kk)] = (f16)v;
    }
  }
  __syncthreads();

  layer_phase< 32, 64>(Hb[0], Hb[1], ztw, wt+0,      bcat+0,    av, Bfrag, w, m, q); __syncthreads();
  layer_phase< 64, 64>(Hb[1], Hb[0], ztw, wt+2048,   bcat+64,   av, Bfrag, w, m, q); __syncthreads();
  layer_phase< 64, 64>(Hb[0], Hb[1], ztw, wt+6144,   bcat+128,  av, Bfrag, w, m, q); __syncthreads();
  layer_phase< 64,128>(Hb[1], Hb[0], ztw, wt+10240,  bcat+192,  av, Bfrag, w, m, q); __syncthreads();
  layer_phase<128,128>(Hb[0], Hb[1], ztw, wt+18432,  bcat+320,  av, Bfrag, w, m, q); __syncthreads();
  layer_phase<128,128>(Hb[1], Hb[0], ztw, wt+34816,  bcat+448,  av, Bfrag, w, m, q); __syncthreads();
  layer_phase<128,256>(Hb[0], Hb[1], ztw, wt+51200,  bcat+576,  av, Bfrag, w, m, q); __syncthreads();
  layer_phase<256,256>(Hb[1], Hb[0], ztw, wt+83968,  bcat+832,  av, Bfrag, w, m, q); __syncthreads();
  layer_phase<256,256>(Hb[0], Hb[1], ztw, wt+149504, bcat+1088, av, Bfrag, w, m, q); __syncthreads();

  // ---- JRPP pooling from Hb[1]: v2h column pairs, 128 threads -------------
  {
    const int k0 = t*2;
    float sA[2]={0,0}, sB[2]={0,0}, sH[2]={0,0}, sL[2]={0,0}, sR[2]={0,0};
    #pragma unroll
    for (int i=0;i<17;++i){
      float hi[2];
      ldh2(&Hb[1][hswz(i, k0)], hi);
      #pragma unroll
      for (int v=0;v<2;++v){
        if (i<11) sA[v]+=hi[v]; else sB[v]+=hi[v];
        if (i<5)  sH[v]+=hi[v];
        if (i==5||i==7||i==9||i==12||i==14||i==16)  sL[v]+=hi[v];
        if (i==6||i==8||i==10||i==11||i==13||i==15) sR[v]+=hi[v];
      }
    }
    f16* op = pooled + (size_t)gg*1536 + k0;
    v2h o;
    #pragma unroll
    for (int v=0;v<2;++v) o[v]=(f16)((sA[v]+sB[v])*(1.0f/17.0f)); *(v2h*)(op+0*256)=o;
    #pragma unroll
    for (int v=0;v<2;++v) o[v]=(f16)(sA[v]*(1.0f/11.0f));         *(v2h*)(op+1*256)=o;
    #pragma unroll
    for (int v=0;v<2;++v) o[v]=(f16)(sB[v]*(1.0f/6.0f));          *(v2h*)(op+2*256)=o;
    #pragma unroll
    for (int v=0;v<2;++v) o[v]=(f16)(sH[v]*(1.0f/5.0f));          *(v2h*)(op+3*256)=o;
    #pragma unroll
    for (int v=0;v<2;++v) o[v]=(f16)(sL[v]*(1.0f/6.0f));          *(v2h*)(op+4*256)=o;
    #pragma unroll
    for (int v=0;v<2;++v) o[v]=(f16)(sR[v]*(1.0f/6.0f));          *(v2h*)(op+5*256)=o;
  }
}

// ---------------- head: stage once, 288 MFMA straight-line, BN + L2-norm -----
__global__ __launch_bounds__(256, 3)
void head_kernel(const f16* __restrict__ pooled, const f16* __restrict__ fcWh,
                 const float* __restrict__ fcB, const float* __restrict__ bnsc,
                 const float* __restrict__ bnsh, float* __restrict__ out, int G)
{
  __shared__ __align__(16) f16 Ap[16*1536];   // 49152 B, swizzled
  __shared__ float red[64];
  __shared__ float invn[16];
  const int t = threadIdx.x, w = t>>6, lane = t&63;
  const int m = lane&15, q = lane>>4;
  const int g0 = blockIdx.x*16;
  const int cb = w*64;

  // stage pooled rows (all 6 scales) once
  for (int id=t; id<16*192; id+=256){
    const int row = id/192, cc = id - row*192;
    v8h v = v8h{0,0,0,0,0,0,0,0};
    const int gg = g0 + row;
    if (gg < G) v = *(const v8h*)(pooled + (size_t)gg*1536 + cc*8);
    const int pc = (cc & ~7) | ((cc&7) ^ (row&7));
    *(v8h*)(Ap + row*1536 + pc*8) = v;
  }
  __syncthreads();

  v4f acc[6][4];
  #pragma unroll
  for (int s=0;s<6;++s)
    #pragma unroll
    for (int nt=0;nt<4;++nt) acc[s][nt] = v4f{0.f,0.f,0.f,0.f};

  #pragma unroll
  for (int s=0;s<6;++s){
    #pragma unroll
    for (int ks=0; ks<8; ++ks){
      const int c = s*32 + ks*4 + q;
      const v8h af = *(const v8h*)(Ap + m*1536 + ((c & ~7) | ((c&7) ^ (m&7)))*8);
      #pragma unroll
      for (int nt=0;nt<4;++nt){
        // B-fragment-packed fcW: wave reads 1KB contiguous per (s,nt,ks)
        const v8h bf = *(const v8h*)(fcWh + (size_t)s*65536 +
                         (((((w*4+nt)*8 + ks)*64) + q*16 + m)<<3));
        acc[s][nt] = __builtin_amdgcn_mfma_f32_16x16x32_f16(af, bf, acc[s][nt], 0,0,0);
      }
    }
  }

  // BN in place + per-graph sum of squares
  float ss[4] = {0.f,0.f,0.f,0.f};
  #pragma unroll
  for (int s=0;s<6;++s)
    #pragma unroll
    for (int nt=0;nt<4;++nt){
      const int idx = s*256 + cb + nt*16 + m;
      const float bc = fcB[idx], sc = bnsc[idx], sh = bnsh[idx];
      #pragma unroll
      for (int i=0;i<4;++i){
        const float f = (acc[s][nt][i] + bc)*sc + sh;
        acc[s][nt][i] = f;
        ss[i] += f*f;
      }
    }

  #pragma unroll
  for (int off=1; off<16; off<<=1)
    #pragma unroll
    for (int i=0;i<4;++i) ss[i] += __shfl_xor(ss[i], off, 64);
  if (m==0)
    #pragma unroll
    for (int i=0;i<4;++i) red[w*16 + q*4 + i] = ss[i];
  __syncthreads();
  if (t < 16){
    const float s4 = red[t] + red[16+t] + red[32+t] + red[48+t];
    invn[t] = 1.f / fmaxf(sqrtf(s4), 1e-12f);
  }
  __syncthreads();
  float iv[4];
  #pragma unroll
  for (int i=0;i<4;++i) iv[i] = invn[q*4+i];
  #pragma unroll
  for (int s=0;s<6;++s)
    #pragma unroll
    for (int nt=0;nt<4;++nt)
      #pragma unroll
      for (int i=0;i<4;++i){
        const int gg = g0 + q*4 + i;
        if (gg < G)
          out[(size_t)gg*1536 + s*256 + cb + nt*16 + m] = acc[s][nt][i]*iv[i];
      }
}

extern "C" void kernel_launch(void* const* d_in, const int* in_sizes, int n_in,
                              void* d_out, int out_size, void* d_ws, size_t ws_size,
                              hipStream_t stream) {
  (void)n_in; (void)out_size; (void)ws_size;
  const float* x   = (const float*)d_in[0];
  const float* att = (const float*)d_in[1];
  const float* W[9]; const float* B[9];
  for (int i=0;i<9;i++){ W[i]=(const float*)d_in[3+2*i]; B[i]=(const float*)d_in[4+2*i]; }
  const float* fcW  = (const float*)d_in[21];
  const float* fcB  = (const float*)d_in[22];
  const float* bn_g = (const float*)d_in[23];
  const float* bn_b = (const float*)d_in[24];
  const float* bn_rm= (const float*)d_in[25];
  const float* bn_rv= (const float*)d_in[26];
  float* out = (float*)d_out;

  const int G = in_sizes[1] / 17;

  // ws layout
  char* ws = (char*)d_ws;
  f16*   wt   = (f16*)(ws);                       // 430080 B
  f16*   fcWh = (f16*)(ws + 430080);              // 786432 B -> ends 1216512
  float* bnsc = (float*)(ws + 1216512);           // 6144 B
  float* bnsh = (float*)(ws + 1222656);           // 6144 B
  float* bcat = (float*)(ws + 1228800);           // 5376 B -> ends 1234176
  f16*   At32 = (f16*)(ws + 1234176);             // 2048 B -> ends 1236224
  float* attp = (float*)(ws + 1236224);           // G*32*4 B
  size_t poolOff = (1236224 + (size_t)G*128 + 255) & ~(size_t)255;
  f16* pooled = (f16*)(ws + poolOff);             // G*1536*2 B

  prep_kernel<<<2048, 256, 0, stream>>>(
      W[0],W[1],W[2],W[3],W[4],W[5],W[6],W[7],W[8],
      B[0],B[1],B[2],B[3],B[4],B[5],B[6],B[7],B[8],
      fcW, bn_g, bn_b, bn_rm, bn_rv, att,
      wt, At32, fcWh, bnsc, bnsh, bcat, attp, G);

  gcn_kernel<<<G, 128, 0, stream>>>(
      x, wt, At32, attp, bcat, pooled, G);

  head_kernel<<<(G + 15)/16, 256, 0, stream>>>(
      pooled, fcWh, fcB, bnsc, bnsh, out, G);
}